// Round 9
// baseline (496.218 us; speedup 1.0000x reference)
//
#include <hip/hip_runtime.h>

// Linear-chain CRF log-partition, B=64, S=1024, T=128.
//
// r20 = r19 (MFMA segment-product scan, 342us, passed) with the DS-traffic
// halving: 64 output rows per wave instead of 32.
//
// r19 counters: seg kernel 287us, DS-issue-bound (128 b128 reads + 64 b64
// writes per block-step = 1920 DS cyc; 491K cyc/CU total = 205us at 100%
// busy; observed 287 -> ~71% busy at 21% occupancy). Bank conflicts are
// the structural 2-deep tally of wave64 b128 (280/block-step) - not a
// lever. The lever: B-read volume per wave = 256B/output-row; doubling
// rows/wave HALVES total DS traffic.
//
// r20 geometry: 2-wave blocks (128 thr), wave owns 64 rows; each block
// owns a 16-column slice of the running product (slices evolve
// independently: M[:,n] <- E' D M[:,n]). Grid (64 b, 16 g, 8 cs) = 8192
// blocks; LDS 2 x 4KB double buffer. Per block-step: 8 ds_read_b128 +
// 8 ds_write_b64 -> total 295K DS-cyc/CU = 123us floor; ~8 blocks/CU
// resident so the DS pipe saturates. Registers: A-frags 64 + C 16 +
// em-prefetch 16 + misc ~= 115 < the observed 132 wall (r19 kept its
// 96-live set; demand that FITS is kept). A-frags additionally pinned
// per-iteration with "+v" asm (0 instrs) against r15-style demotion.
// Gate: VGPR_Count >= 104, else allocator betrayal.
//
// Numerics IDENTICAL to r19 (passed, absmax 0.0): E' = exp(trans)*e^-GHAT
// f16 A-side; per-step publish = f16(acc * exp(em_next)); f32 MFMA accum;
// combine kernel applies 16 segment matrices + GHAT*count + LSE.
//
// Workspace: 64*16*128*128 f16 = 32 MB of d_ws.

typedef _Float16 h8  __attribute__((ext_vector_type(8)));
typedef float    f4  __attribute__((ext_vector_type(4)));
typedef unsigned u4v __attribute__((ext_vector_type(4)));

#define B_  64
#define S_  1024
#define T_  128
#define G_  16
#define CS_ 8       // column slices per segment
#define N_  16      // cols per block
#define PAD_IDX 0
#define EOS_IDX 3
#define BOT_IDX 1
#define GHAT         5.35f
#define EXP_NEG_GHAT 0.004736892f   // e^{-5.35}

// swizzled LDS byte offset for B element (n = local col 0..15, ks = k>>3).
__device__ __forceinline__ int baddr16(int n, int ks) {
  return n * 256 + (((ks ^ n) & 15) << 4);
}

// ---------------- kernel 1: per-segment column-slice product ----------------
__global__ __launch_bounds__(128)
void crf_seg_kernel(const int* __restrict__ W,
                    const float* __restrict__ emissions,
                    const float* __restrict__ transitions,
                    _Float16* __restrict__ ws)
{
  const int b = blockIdx.x, g = blockIdx.y, cs = blockIdx.z;
  const int tid  = threadIdx.x;     // 0..127 — two waves
  const int w    = tid >> 6;        // wave 0/1 -> rows [64w, 64w+64)
  const int lane = tid & 63;
  const int lr   = lane & 15;       // row-in-tile (A) / col (B,C)
  const int lg   = lane >> 4;       // 8-wide K group (A,B) / 4-row group (C)

  __shared__ __align__(16) char bbuf[2][4096];    // 16 cols x 256 B, dbuf

  // --- segment activity mask (identical in both waves)
  int tok = W[b * S_ + g * 64 + lane];
  unsigned long long mask = __ballot((tok != PAD_IDX) & (tok != EOS_IDX));
  if (g == 0) mask &= ~1ull;                      // i==0 is never consumed

  const size_t segoff = ((size_t)(b * G_ + g)) << 14;   // 16384 f16/segment

  if (mask == 0ull) {                             // empty: S_g slice = I slice
    _Float16 vals[16];
    #pragma unroll
    for (int e = 0; e < 16; ++e)
      vals[e] = (tid == 16 * cs + e) ? (_Float16)1.f : (_Float16)0.f;
    *(h8*)(ws + segoff + (size_t)tid * T_ + 16 * cs)     = *(h8*)&vals[0];
    *(h8*)(ws + segoff + (size_t)tid * T_ + 16 * cs + 8) = *(h8*)&vals[8];
    return;
  }

  // --- A operand: E' rows [64w, 64w+64): EA[rtl][kb] =
  //     A[row = 64w+16rtl+lr][k = kb*32 + lg*8 + j]   (16 h8 = 64 VGPRs)
  u4v EA[4][4];
  #pragma unroll
  for (int rtl = 0; rtl < 4; ++rtl) {
    const int row = 64 * w + 16 * rtl + lr;
    #pragma unroll
    for (int kb = 0; kb < 4; ++kb) {
      const float4* tp = (const float4*)(transitions + (size_t)row * T_ + kb * 32 + lg * 8);
      float4 x = tp[0], y = tp[1];
      h8 f;
      f[0] = (_Float16)(__expf(x.x) * EXP_NEG_GHAT);
      f[1] = (_Float16)(__expf(x.y) * EXP_NEG_GHAT);
      f[2] = (_Float16)(__expf(x.z) * EXP_NEG_GHAT);
      f[3] = (_Float16)(__expf(x.w) * EXP_NEG_GHAT);
      f[4] = (_Float16)(__expf(y.x) * EXP_NEG_GHAT);
      f[5] = (_Float16)(__expf(y.y) * EXP_NEG_GHAT);
      f[6] = (_Float16)(__expf(y.z) * EXP_NEG_GHAT);
      f[7] = (_Float16)(__expf(y.w) * EXP_NEG_GHAT);
      EA[rtl][kb] = __builtin_bit_cast(u4v, f);
    }
  }

  // --- init Bbuf[0] = diag(exp(em[i_hi]))[:, 16cs..16cs+15]
  const int hib = 63 - __builtin_clzll(mask);
  *(uint4*)(&bbuf[0][tid * 32])      = uint4{0u, 0u, 0u, 0u};
  *(uint4*)(&bbuf[0][tid * 32 + 16]) = uint4{0u, 0u, 0u, 0u};
  __syncthreads();
  if (tid < N_) {
    int k = 16 * cs + tid;                        // diag row for local col tid
    float e = emissions[((size_t)b * S_ + (g * 64 + hib)) * T_ + k];
    *(_Float16*)(&bbuf[0][baddr16(tid, k >> 3) + (k & 7) * 2]) = (_Float16)__expf(e);
  }

  // --- next-active scan + em prefetch (one step ahead)
  unsigned long long rem = mask & ~(1ull << hib);
  int inb = rem ? (63 - __builtin_clzll(rem)) : -1;
  float4 epf[4];
  {
    int idx = (inb < 0) ? 0 : (g * 64 + inb);
    const float* ep = emissions + ((size_t)b * S_ + idx) * T_;
    #pragma unroll
    for (int rtl = 0; rtl < 4; ++rtl)
      epf[rtl] = *(const float4*)(ep + 64 * w + 16 * rtl + 4 * lg);
  }

  int p = 0;
  f4 acc[4];
  for (;;) {
    // pin A residency (0 instructions; demand ~115 fits the budget)
    #pragma unroll
    for (int rtl = 0; rtl < 4; ++rtl)
      #pragma unroll
      for (int kb = 0; kb < 4; ++kb)
        asm volatile("" : "+v"(EA[rtl][kb]));

    __syncthreads();                              // Bbuf[p] ready

    #pragma unroll
    for (int rtl = 0; rtl < 4; ++rtl) acc[rtl] = f4{0.f, 0.f, 0.f, 0.f};

    #pragma unroll
    for (int kb = 0; kb < 4; ++kb) {
      h8 bf = *(const h8*)(&bbuf[p][baddr16(lr, kb * 4 + lg)]);
      #pragma unroll
      for (int rtl = 0; rtl < 4; ++rtl)
        acc[rtl] = __builtin_amdgcn_mfma_f32_16x16x32_f16(
            __builtin_bit_cast(h8, EA[rtl][kb]), bf, acc[rtl], 0, 0, 0);
    }

    if (inb < 0) break;                           // acc = S_g slice, done

    rem &= ~(1ull << inb);
    int inn = rem ? (63 - __builtin_clzll(rem)) : -1;
    float4 ecur[4];
    #pragma unroll
    for (int rtl = 0; rtl < 4; ++rtl) ecur[rtl] = epf[rtl];
    {
      int idx = (inn < 0) ? 0 : (g * 64 + inn);   // clamp; unused if -1
      const float* ep = emissions + ((size_t)b * S_ + idx) * T_;
      #pragma unroll
      for (int rtl = 0; rtl < 4; ++rtl)
        epf[rtl] = *(const float4*)(ep + 64 * w + 16 * rtl + 4 * lg);
    }

    // publish Bbuf[p^1][k][lr] = exp(em)*acc for k = 64w+16rtl+4lg+{0..3}
    #pragma unroll
    for (int rtl = 0; rtl < 4; ++rtl) {
      const int k0 = 64 * w + 16 * rtl + 4 * lg;
      f4 c = acc[rtl];
      float4 e = ecur[rtl];
      uint2 d;
      d.x = __builtin_bit_cast(unsigned,
              __builtin_amdgcn_cvt_pkrtz(c[0] * __expf(e.x), c[1] * __expf(e.y)));
      d.y = __builtin_bit_cast(unsigned,
              __builtin_amdgcn_cvt_pkrtz(c[2] * __expf(e.z), c[3] * __expf(e.w)));
      *(uint2*)(&bbuf[p ^ 1][baddr16(lr, k0 >> 3) + (k0 & 7) * 2]) = d;
    }
    p ^= 1;
    inb = inn;
  }

  // --- store S_g slice (unscaled acc) to workspace, row-major f16
  #pragma unroll
  for (int rtl = 0; rtl < 4; ++rtl) {
    const int k0 = 64 * w + 16 * rtl + 4 * lg;
    #pragma unroll
    for (int r = 0; r < 4; ++r)
      ws[segoff + (size_t)(k0 + r) * T_ + 16 * cs + lr] = (_Float16)acc[rtl][r];
  }
}

// ---------------- kernel 2: combine segments + epilogue ----------------
__global__ __launch_bounds__(128)
void crf_combine_kernel(const int* __restrict__ W,
                        const float* __restrict__ emissions,
                        const float* __restrict__ transitions,
                        const _Float16* __restrict__ ws,
                        float* __restrict__ out)
{
  const int b = blockIdx.x, t = threadIdx.x;
  __shared__ float qv[T_];
  __shared__ float redf[128];
  __shared__ int   redi[128];

  qv[t] = 1.0f;
  __syncthreads();

  // apply S_15 first, S_0 last:  q = S_0 S_1 ... S_15 * 1
  for (int g = G_ - 1; g >= 0; --g) {
    const _Float16* Sg = ws + (((size_t)(b * G_ + g)) << 14) + (size_t)t * T_;
    float acc = 0.f;
    #pragma unroll
    for (int j8 = 0; j8 < 16; ++j8) {
      h8 v = *(const h8*)(Sg + j8 * 8);
      float4 q0 = *(const float4*)&qv[j8 * 8];
      float4 q1 = *(const float4*)&qv[j8 * 8 + 4];
      acc += (float)v[0] * q0.x + (float)v[1] * q0.y
           + (float)v[2] * q0.z + (float)v[3] * q0.w
           + (float)v[4] * q1.x + (float)v[5] * q1.y
           + (float)v[6] * q1.z + (float)v[7] * q1.w;
    }
    __syncthreads();
    qv[t] = acc;
    __syncthreads();
  }

  // k = number of active steps (i in [1,1023]) for the GHAT compensation
  int cnt = 0;
  #pragma unroll
  for (int c = 0; c < 8; ++c) {
    int i = c * 128 + t;
    if (i >= 1) {
      int tk = W[b * S_ + i];
      cnt += ((tk != PAD_IDX) & (tk != EOS_IDX)) ? 1 : 0;
    }
  }

  float term = __expf(transitions[BOT_IDX * T_ + t]
                      + emissions[(size_t)b * S_ * T_ + t]) * qv[t];
  redf[t] = term;
  redi[t] = cnt;
  __syncthreads();
  #pragma unroll
  for (int off = 64; off > 0; off >>= 1) {
    if (t < off) { redf[t] += redf[t + off]; redi[t] += redi[t + off]; }
    __syncthreads();
  }
  if (t == 0) out[b] = GHAT * (float)redi[0] + logf(redf[0]);
}

extern "C" void kernel_launch(void* const* d_in, const int* in_sizes, int n_in,
                              void* d_out, int out_size, void* d_ws, size_t ws_size,
                              hipStream_t stream) {
  const int*   W     = (const int*)d_in[0];
  const float* em    = (const float*)d_in[1];
  const float* trans = (const float*)d_in[2];
  float*       out   = (float*)d_out;
  _Float16*    wsp   = (_Float16*)d_ws;          // needs 32 MB
  (void)in_sizes; (void)n_in; (void)out_size; (void)ws_size;

  crf_seg_kernel<<<dim3(B_, G_, CS_), 128, 0, stream>>>(W, em, trans, wsp);
  crf_combine_kernel<<<B_, 128, 0, stream>>>(W, em, trans, wsp, out);
}

// Round 11
// 365.075 us; speedup vs baseline: 1.3592x; 1.3592x over previous
//
#include <hip/hip_runtime.h>

// Linear-chain CRF log-partition, B=64, S=1024, T=128.
//
// r22 = r21 resubmitted verbatim (r21 bench was an infra failure:
// "MI355X container failed twice" — no compile/run/counters).
//
// r21 = r19 (287us seg, passed) with intra-block DS-traffic halving.
//
// r20 post-mortem: col-splitting ACROSS blocks (8192 blocks) duplicated
// em fetch (FETCH 16.8->128.8 MB) and exp (VALU 43->56%) 8x -> 460us.
// Lesson: split columns INSIDE the block. Fixed floors: MFMA 275 GFLOP ->
// 110us @ 100% util; r19 DS 205us. r21 balances them:
//
//  - 1024 blocks (64 b x 16 g), 512 thr = 8 waves = 2 row-groups x 4
//    col-groups; wave owns a 64x32 C quadrant. B-read/wave = 8 KB (vs
//    r19's 32): DS/block-step 1920 -> ~1344 cyc -> ~143us floor, MFMA
//    1242 cyc -> 132us; overlapped floor ~150us.
//  - exp(em) computed ONCE per block into a 16 KB LDS U-chunk (f16) at
//    block start: zero in-loop transcendentals; in-loop U read is a
//    16-lane-broadcast ds_read_b64 (conflict-free).
//  - LDS = 2x32KB B dbuf + 16KB U = 80 KB -> exactly 2 blocks/CU.
//  - __launch_bounds__(512,4): hard 128-VGPR cap; demand ~120 fits
//    (EA 64 + acc 32 + transients). EA pinned per-iter with "+v".
//
// Numerics = r19/r20 (both passed, absmax 0.0) + one extra f16 rounding
// on exp(em) (same class as the existing cvt_pkrtz chain).
// Workspace: 32 MB (segment matrices only; U now lives in LDS).

typedef _Float16 h8  __attribute__((ext_vector_type(8)));
typedef _Float16 hv2 __attribute__((ext_vector_type(2)));
typedef float    f4  __attribute__((ext_vector_type(4)));
typedef unsigned u4v __attribute__((ext_vector_type(4)));

#define B_  64
#define S_  1024
#define T_  128
#define G_  16
#define PAD_IDX 0
#define EOS_IDX 3
#define BOT_IDX 1
#define GHAT         5.35f
#define EXP_NEG_GHAT 0.004736892f   // e^{-5.35}

// swizzled LDS byte offset for B element (n = col 0..127, ks = k>>3)
__device__ __forceinline__ int baddr16(int n, int ks) {
  return n * 256 + (((ks ^ n) & 15) << 4);
}

// ---------------- kernel 1: per-segment matrix product ----------------
__global__ __launch_bounds__(512, 4)
void crf_seg_kernel(const int* __restrict__ W,
                    const float* __restrict__ emissions,
                    const float* __restrict__ transitions,
                    _Float16* __restrict__ ws)
{
  const int b = blockIdx.x, g = blockIdx.y;
  const int tid  = threadIdx.x;     // 0..511 — eight waves
  const int w    = tid >> 6;
  const int rg   = w >> 2;          // row group 0..1 -> rows [64rg, 64rg+64)
  const int cg   = w & 3;           // col group 0..3 -> cols [32cg, 32cg+32)
  const int lane = tid & 63;
  const int lr   = lane & 15;       // row-in-tile (A) / col (B,C)
  const int lg   = lane >> 4;       // 8-K group (A,B) / 4-row group (C)

  __shared__ __align__(16) char     bbuf[2][32768];   // B operand, dbuf
  __shared__ __align__(16) _Float16 uld[64 * T_];     // exp(em) chunk, f16

  // --- segment activity mask (identical in all waves)
  int tok = W[b * S_ + g * 64 + lane];
  unsigned long long mask = __ballot((tok != PAD_IDX) & (tok != EOS_IDX));
  if (g == 0) mask &= ~1ull;                      // i==0 is never consumed

  const size_t segoff = ((size_t)(b * G_ + g)) << 14;   // 16384 f16/segment

  if (mask == 0ull) {                             // empty segment: S_g = I
    int r = tid >> 2, c0 = (tid & 3) << 5;
    #pragma unroll
    for (int e8 = 0; e8 < 4; ++e8) {
      h8 v;
      #pragma unroll
      for (int e = 0; e < 8; ++e)
        v[e] = (r == c0 + e8 * 8 + e) ? (_Float16)1.f : (_Float16)0.f;
      *(h8*)(ws + segoff + (size_t)r * T_ + c0 + e8 * 8) = v;
    }
    return;
  }

  // --- A operand: E' = exp(trans)*e^-GHAT, rows [64rg, 64rg+64)
  // EA[rtl][kb] = A[row = 64rg+16rtl+lr][k = kb*32 + lg*8 + j]  (64 VGPRs)
  u4v EA[4][4];
  #pragma unroll
  for (int rtl = 0; rtl < 4; ++rtl) {
    const int row = 64 * rg + 16 * rtl + lr;
    #pragma unroll
    for (int kb = 0; kb < 4; ++kb) {
      const float4* tp = (const float4*)(transitions + (size_t)row * T_ + kb * 32 + lg * 8);
      float4 x = tp[0], y = tp[1];
      h8 f;
      f[0] = (_Float16)(__expf(x.x) * EXP_NEG_GHAT);
      f[1] = (_Float16)(__expf(x.y) * EXP_NEG_GHAT);
      f[2] = (_Float16)(__expf(x.z) * EXP_NEG_GHAT);
      f[3] = (_Float16)(__expf(x.w) * EXP_NEG_GHAT);
      f[4] = (_Float16)(__expf(y.x) * EXP_NEG_GHAT);
      f[5] = (_Float16)(__expf(y.y) * EXP_NEG_GHAT);
      f[6] = (_Float16)(__expf(y.z) * EXP_NEG_GHAT);
      f[7] = (_Float16)(__expf(y.w) * EXP_NEG_GHAT);
      EA[rtl][kb] = __builtin_bit_cast(u4v, f);
    }
  }

  // --- stage U = f16(exp(em-chunk)) into LDS (coalesced, once per block)
  {
    const float4* emc = (const float4*)(emissions + ((size_t)b * S_ + g * 64) * T_);
    #pragma unroll
    for (int k = 0; k < 4; ++k) {
      int f = tid + k * 512;                     // float4 index in [0, 2048)
      float4 v = emc[f];
      uint2 d;
      d.x = __builtin_bit_cast(unsigned,
              __builtin_amdgcn_cvt_pkrtz(__expf(v.x), __expf(v.y)));
      d.y = __builtin_bit_cast(unsigned,
              __builtin_amdgcn_cvt_pkrtz(__expf(v.z), __expf(v.w)));
      *(uint2*)&uld[f * 4] = d;
    }
  }
  // zero Bbuf[0] (diag init is sparse)
  {
    char* bz = &bbuf[0][0] + tid * 64;
    #pragma unroll
    for (int r = 0; r < 4; ++r) *(uint4*)(bz + r * 16) = uint4{0u,0u,0u,0u};
  }
  __syncthreads();

  // --- init Bbuf[0] = diag(U[hib])
  const int hib = 63 - __builtin_clzll(mask);
  if (tid < T_) {
    _Float16 u = uld[hib * T_ + tid];
    *(_Float16*)(&bbuf[0][tid * 256 + (((tid >> 3) ^ tid) & 15) * 16 + (tid & 7) * 2]) = u;
  }

  unsigned long long rem = mask & ~(1ull << hib);
  int inb = rem ? (63 - __builtin_clzll(rem)) : -1;

  int p = 0;
  f4 acc[4][2];
  for (;;) {
    // pin EA residency (0 instructions; demand fits the 128 cap)
    #pragma unroll
    for (int rtl = 0; rtl < 4; ++rtl)
      #pragma unroll
      for (int kb = 0; kb < 4; ++kb)
        asm volatile("" : "+v"(EA[rtl][kb]));

    __syncthreads();                              // Bbuf[p] ready

    #pragma unroll
    for (int rtl = 0; rtl < 4; ++rtl)
      #pragma unroll
      for (int ct = 0; ct < 2; ++ct) acc[rtl][ct] = f4{0.f, 0.f, 0.f, 0.f};

    #pragma unroll
    for (int kb = 0; kb < 4; ++kb) {
      #pragma unroll
      for (int ct = 0; ct < 2; ++ct) {
        const int n = 32 * cg + 16 * ct + lr;
        h8 bf = *(const h8*)(&bbuf[p][baddr16(n, kb * 4 + lg)]);
        #pragma unroll
        for (int rtl = 0; rtl < 4; ++rtl)
          acc[rtl][ct] = __builtin_amdgcn_mfma_f32_16x16x32_f16(
              __builtin_bit_cast(h8, EA[rtl][kb]), bf, acc[rtl][ct], 0, 0, 0);
      }
    }

    if (inb < 0) break;                           // acc = S_g quadrant, done

    const int step = inb;
    rem &= ~(1ull << inb);
    const int inn = rem ? (63 - __builtin_clzll(rem)) : -1;

    // publish Bbuf[p^1] = diag(U[step]) * acc  (f16, swizzled)
    #pragma unroll
    for (int rtl = 0; rtl < 4; ++rtl) {
      const int k0 = 64 * rg + 16 * rtl + 4 * lg;
      uint2 up = *(const uint2*)&uld[step * T_ + k0];   // broadcast b64
      hv2 u01 = __builtin_bit_cast(hv2, up.x);
      hv2 u23 = __builtin_bit_cast(hv2, up.y);
      #pragma unroll
      for (int ct = 0; ct < 2; ++ct) {
        const int n = 32 * cg + 16 * ct + lr;
        f4 c = acc[rtl][ct];
        hv2 lo = __builtin_bit_cast(hv2,
                   __builtin_amdgcn_cvt_pkrtz(c[0], c[1])) * u01;
        hv2 hi = __builtin_bit_cast(hv2,
                   __builtin_amdgcn_cvt_pkrtz(c[2], c[3])) * u23;
        uint2 d;
        d.x = __builtin_bit_cast(unsigned, lo);
        d.y = __builtin_bit_cast(unsigned, hi);
        *(uint2*)(&bbuf[p ^ 1][n * 256 + (((k0 >> 3) ^ n) & 15) * 16 + (k0 & 7) * 2]) = d;
      }
    }
    p ^= 1;
    inb = inn;
  }

  // --- store S_g quadrant (unscaled acc) to workspace, row-major f16
  #pragma unroll
  for (int rtl = 0; rtl < 4; ++rtl) {
    const int k0 = 64 * rg + 16 * rtl + 4 * lg;
    #pragma unroll
    for (int ct = 0; ct < 2; ++ct) {
      const int n = 32 * cg + 16 * ct + lr;
      #pragma unroll
      for (int r = 0; r < 4; ++r)
        ws[segoff + (size_t)(k0 + r) * T_ + n] = (_Float16)acc[rtl][ct][r];
    }
  }
}

// ---------------- kernel 2: combine segments + epilogue ----------------
__global__ __launch_bounds__(128)
void crf_combine_kernel(const int* __restrict__ W,
                        const float* __restrict__ emissions,
                        const float* __restrict__ transitions,
                        const _Float16* __restrict__ ws,
                        float* __restrict__ out)
{
  const int b = blockIdx.x, t = threadIdx.x;
  __shared__ float qv[T_];
  __shared__ float redf[128];
  __shared__ int   redi[128];

  qv[t] = 1.0f;
  __syncthreads();

  // apply S_15 first, S_0 last:  q = S_0 S_1 ... S_15 * 1
  for (int g = G_ - 1; g >= 0; --g) {
    const _Float16* Sg = ws + (((size_t)(b * G_ + g)) << 14) + (size_t)t * T_;
    float acc = 0.f;
    #pragma unroll
    for (int j8 = 0; j8 < 16; ++j8) {
      h8 v = *(const h8*)(Sg + j8 * 8);
      float4 q0 = *(const float4*)&qv[j8 * 8];
      float4 q1 = *(const float4*)&qv[j8 * 8 + 4];
      acc += (float)v[0] * q0.x + (float)v[1] * q0.y
           + (float)v[2] * q0.z + (float)v[3] * q0.w
           + (float)v[4] * q1.x + (float)v[5] * q1.y
           + (float)v[6] * q1.z + (float)v[7] * q1.w;
    }
    __syncthreads();
    qv[t] = acc;
    __syncthreads();
  }

  // count of active steps (i in [1,1023]) for the GHAT compensation
  int cnt = 0;
  #pragma unroll
  for (int c = 0; c < 8; ++c) {
    int i = c * 128 + t;
    if (i >= 1) {
      int tk = W[b * S_ + i];
      cnt += ((tk != PAD_IDX) & (tk != EOS_IDX)) ? 1 : 0;
    }
  }

  float term = __expf(transitions[BOT_IDX * T_ + t]
                      + emissions[(size_t)b * S_ * T_ + t]) * qv[t];
  redf[t] = term;
  redi[t] = cnt;
  __syncthreads();
  #pragma unroll
  for (int off = 64; off > 0; off >>= 1) {
    if (t < off) { redf[t] += redf[t + off]; redi[t] += redi[t + off]; }
    __syncthreads();
  }
  if (t == 0) out[b] = GHAT * (float)redi[0] + logf(redf[0]);
}

extern "C" void kernel_launch(void* const* d_in, const int* in_sizes, int n_in,
                              void* d_out, int out_size, void* d_ws, size_t ws_size,
                              hipStream_t stream) {
  const int*   W     = (const int*)d_in[0];
  const float* em    = (const float*)d_in[1];
  const float* trans = (const float*)d_in[2];
  float*       out   = (float*)d_out;
  _Float16*    wsp   = (_Float16*)d_ws;          // needs 32 MB
  (void)in_sizes; (void)n_in; (void)out_size; (void)ws_size;

  crf_seg_kernel<<<dim3(B_, G_), 512, 0, stream>>>(W, em, trans, wsp);
  crf_combine_kernel<<<B_, 128, 0, stream>>>(W, em, trans, wsp, out);
}